// Round 1
// baseline (8930.396 us; speedup 1.0000x reference)
//
#include <hip/hip_runtime.h>
#include <math.h>
#include <stdint.h>

#define PI_ 3.14159265358979323846

// ---------------- threefry2x32 (JAX-compatible) ----------------
__host__ __device__ inline void tf2x32(uint32_t k0, uint32_t k1, uint32_t x0, uint32_t x1,
                                       uint32_t& o0, uint32_t& o1) {
  uint32_t k2 = k0 ^ k1 ^ 0x1BD11BDAu;
  uint32_t v0 = x0 + k0, v1 = x1 + k1;
#define TF_R(r) { v0 += v1; v1 = ((v1 << (r)) | (v1 >> (32 - (r)))); v1 ^= v0; }
  TF_R(13) TF_R(15) TF_R(26) TF_R(6)
  v0 += k1; v1 += k2 + 1u;
  TF_R(17) TF_R(29) TF_R(16) TF_R(24)
  v0 += k2; v1 += k0 + 2u;
  TF_R(13) TF_R(15) TF_R(26) TF_R(6)
  v0 += k0; v1 += k1 + 3u;
  TF_R(17) TF_R(29) TF_R(16) TF_R(24)
  v0 += k1; v1 += k2 + 4u;
  TF_R(13) TF_R(15) TF_R(26) TF_R(6)
  v0 += k2; v1 += k0 + 5u;
#undef TF_R
  o0 = v0; o1 = v1;
}

// ---------------- LN over L + forward FFT(1024), f64 ----------------
__global__ __launch_bounds__(256) void ln_fft_kernel(const float* __restrict__ x,
    const float* __restrict__ in_w, const float* __restrict__ in_b,
    double* __restrict__ xr, double* __restrict__ xi) {
  __shared__ double re[1024], im[1024];
  __shared__ double tw[512][2];
  __shared__ double red[256];
  int tid = threadIdx.x, row = blockIdx.x;
  int b = row >> 5, c = row & 31;
  for (int k = tid; k < 512; k += 256) {
    double a = -2.0 * PI_ * (double)k / 1024.0;
    tw[k][0] = cos(a); tw[k][1] = sin(a);
  }
  double s = 0.0;
  for (int l = tid; l < 1024; l += 256) {
    double v = (double)x[(b * 1024 + l) * 32 + c];
    re[l] = v; s += v;
  }
  red[tid] = s; __syncthreads();
  for (int o = 128; o > 0; o >>= 1) { if (tid < o) red[tid] += red[tid + o]; __syncthreads(); }
  double mean = red[0] / 1024.0;
  __syncthreads();
  double s2 = 0.0;
  for (int l = tid; l < 1024; l += 256) { double d = re[l] - mean; s2 += d * d; }
  red[tid] = s2; __syncthreads();
  for (int o = 128; o > 0; o >>= 1) { if (tid < o) red[tid] += red[tid + o]; __syncthreads(); }
  double var = red[0] / 1024.0;
  double scl = (double)in_w[c] / sqrt(var + 1e-5);
  double shf = (double)in_b[c];
  __syncthreads();
  for (int l = tid; l < 1024; l += 256) { re[l] = (re[l] - mean) * scl + shf; im[l] = 0.0; }
  __syncthreads();
  for (int i = tid; i < 1024; i += 256) {
    int j = __brev(i) >> 22;
    if (j > i) { double t = re[i]; re[i] = re[j]; re[j] = t; t = im[i]; im[i] = im[j]; im[j] = t; }
  }
  __syncthreads();
  for (int st = 0; st < 10; st++) {
    int half = 1 << st, tstep = 512 >> st;
    for (int bf = tid; bf < 512; bf += 256) {
      int grp = bf >> st, pos = bf & (half - 1);
      int i0 = (grp << (st + 1)) + pos, i1 = i0 + half;
      double wr = tw[pos * tstep][0], wi = tw[pos * tstep][1];
      double ar = re[i1], ai = im[i1];
      double tr = wr * ar - wi * ai, ti = wr * ai + wi * ar;
      re[i1] = re[i0] - tr; im[i1] = im[i0] - ti;
      re[i0] += tr; im[i0] += ti;
    }
    __syncthreads();
  }
  for (int l = tid; l < 1024; l += 256) { xr[row * 1024 + l] = re[l]; xi[row * 1024 + l] = im[l]; }
}

// ---------------- patches -> z (f64 accum, f32 store) ----------------
__global__ __launch_bounds__(256) void patch_proj_kernel(const double* __restrict__ xr,
    const double* __restrict__ xi, const float* __restrict__ proj_w,
    const float* __restrict__ proj_b, float* __restrict__ z) {
  __shared__ double pr[32][16], pi[32][16];
  __shared__ float pw[32][256];
  int tid = threadIdx.x, bp = blockIdx.x;
  int b = bp / 127, p = bp % 127;
  for (int t = tid; t < 512; t += 256) {
    int c = t >> 4, q = t & 15;
    pr[c][q] = xr[(b * 32 + c) * 1024 + p * 8 + q];
    pi[c][q] = xi[(b * 32 + c) * 1024 + p * 8 + q];
  }
  for (int t = tid; t < 8192; t += 256) pw[t >> 8][t & 255] = proj_w[t];
  __syncthreads();
  int h = tid;
  for (int c = 0; c < 32; c++) {
    double acc = (double)proj_b[h];
#pragma unroll
    for (int q = 0; q < 16; q++)
      acc += pr[c][q] * (double)pw[q][h] + pi[c][q] * (double)pw[16 + q][h];
    z[(bp * 32 + c) * 256 + h] = (float)acc;
  }
}

// ---------------- fold mg_w2 mean over last C ----------------
__global__ __launch_bounds__(256) void w2m_kernel(const float* __restrict__ mg_w2,
    const float* __restrict__ mg_b2, double* __restrict__ w2m, double* __restrict__ b2m) {
  int t = blockIdx.x * 256 + threadIdx.x;
  if (t < 8192) {
    int k = t >> 5, e = t & 31;
    double s = 0.0;
    for (int j = 0; j < 32; j++) s += (double)mg_w2[k * 1024 + e * 32 + j];
    w2m[k * 32 + e] = s / 32.0;
  } else if (t < 8224) {
    int e = t - 8192;
    double s = 0.0;
    for (int j = 0; j < 32; j++) s += (double)mg_b2[e * 32 + j];
    b2m[e] = s / 32.0;
  }
}

// ---------------- mask gate: h1(f64) -> logits -> gumbel threshold ----------------
__global__ __launch_bounds__(256) void mask_kernel(const float* __restrict__ z,
    const float* __restrict__ w1, const float* __restrict__ b1,
    const double* __restrict__ w2m, const double* __restrict__ b2m,
    uint32_t fk0, uint32_t fk1, float* __restrict__ mask, float* __restrict__ out3) {
  __shared__ float ztT[256][32];
  __shared__ float h1[32][256];
  int tid = threadIdx.x, bp = blockIdx.x;
  {
    int c = tid >> 3, k0 = (tid & 7) * 32;
    const float* zp = z + (bp * 32 + c) * 256 + k0;
    for (int i = 0; i < 32; i++) ztT[k0 + i][c] = zp[i];
  }
  __syncthreads();
  {
    double acc[32];
    double bb = (double)b1[tid];
#pragma unroll
    for (int c = 0; c < 32; c++) acc[c] = bb;
    for (int k = 0; k < 256; k++) {
      double wv = (double)w1[k * 256 + tid];
      const float4* z4 = (const float4*)&ztT[k][0];
#pragma unroll
      for (int j = 0; j < 8; j++) {
        float4 v = z4[j];
        acc[j * 4 + 0] += (double)v.x * wv;
        acc[j * 4 + 1] += (double)v.y * wv;
        acc[j * 4 + 2] += (double)v.z * wv;
        acc[j * 4 + 3] += (double)v.w * wv;
      }
    }
#pragma unroll
    for (int c = 0; c < 32; c++) h1[c][tid] = (float)fmax(acc[c], 0.0);
  }
  __syncthreads();
  for (int i = 0; i < 4; i++) {
    int o = tid + i * 256;
    int c = o >> 5, e = o & 31;
    double acc = b2m[e];
    for (int k = 0; k < 256; k++) acc += (double)h1[c][k] * w2m[k * 32 + e];
    // mimic f32 reference op chain with correctly-rounded steps
    float logit = (float)acc;
    float prob = (float)(1.0 / (1.0 + exp(-(double)logit)));
    unsigned idx = (unsigned)bp * 1024u + (unsigned)o;
    uint32_t o0, o1;
    tf2x32(fk0, fk1, 0u, idx, o0, o1);
    uint32_t bits = o0 ^ o1;
    float u = __uint_as_float((bits >> 9) | 0x3f800000u) - 1.0f;
    float t0 = u + 1e-10f;
    float l0 = (float)log((double)t0);
    float t1 = -l0 + 1e-10f;
    float g = -(float)log((double)t1);
    float sarg = prob + g;
    float ys = (float)(1.0 / (1.0 + exp(-(double)sarg)));
    float mv = (c == e || ys > 0.5f) ? 1.0f : 0.0f;
    mask[idx] = mv;
    out3[idx] = mv;
  }
}

// ---------------- fused LN + QKV + masked attention per (b,p) ----------------
__global__ __launch_bounds__(256) void attn_kernel(const float* __restrict__ z,
    const float* __restrict__ lnw, const float* __restrict__ lnb,
    const float* __restrict__ wq, const float* __restrict__ bq,
    const float* __restrict__ wk, const float* __restrict__ bk,
    const float* __restrict__ wv, const float* __restrict__ bv,
    const float* __restrict__ mask, float* __restrict__ ao,
    float* __restrict__ out4, float* __restrict__ out5) {
  __shared__ float znT[256][36];
  __shared__ float Qh[32][36], Kh[32][36], Vh[32][36];
  __shared__ float Sm[32][36];
  __shared__ float red[32][8];
  int tid = threadIdx.x, bp = blockIdx.x;
  int c = tid >> 3, lane8 = tid & 7;
  const float* zrow = z + (bp * 32 + c) * 256;
  float vals[32];
  float s = 0.f;
  for (int j = 0; j < 32; j++) { float v = zrow[lane8 * 32 + j]; vals[j] = v; s += v; }
  red[c][lane8] = s; __syncthreads();
  float mean;
  { float t = 0.f; for (int j = 0; j < 8; j++) t += red[c][j]; mean = t / 256.0f; }
  __syncthreads();
  float s2 = 0.f;
  for (int j = 0; j < 32; j++) { float d = vals[j] - mean; s2 += d * d; }
  red[c][lane8] = s2; __syncthreads();
  float varv;
  { float t = 0.f; for (int j = 0; j < 8; j++) t += red[c][j]; varv = t / 256.0f; }
  float rstd = 1.0f / sqrtf(varv + 1e-5f);
  for (int j = 0; j < 32; j++) {
    int k = lane8 * 32 + j;
    znT[k][c] = (vals[j] - mean) * rstd * lnw[k] + lnb[k];
  }
  __syncthreads();

  float am[4] = {0, 0, 0, 0}, mm[4] = {0, 0, 0, 0};
  int d = tid & 31, cg = tid >> 5;
  const float scale = 0.17677669529663687f;
  for (int h = 0; h < 8; h++) {
    float aq[4], ak[4], av[4];
    {
      float bqv = bq[h * 32 + d], bkv = bk[h * 32 + d], bvv = bv[h * 32 + d];
#pragma unroll
      for (int i = 0; i < 4; i++) { aq[i] = bqv; ak[i] = bkv; av[i] = bvv; }
    }
    const float* wqp = wq + h * 32 + d;
    const float* wkp = wk + h * 32 + d;
    const float* wvp = wv + h * 32 + d;
#pragma unroll 2
    for (int k = 0; k < 256; k++) {
      float4 zv = *(const float4*)&znT[k][cg * 4];
      float wqv = wqp[k * 256], wkv = wkp[k * 256], wvv = wvp[k * 256];
      aq[0] += zv.x * wqv; aq[1] += zv.y * wqv; aq[2] += zv.z * wqv; aq[3] += zv.w * wqv;
      ak[0] += zv.x * wkv; ak[1] += zv.y * wkv; ak[2] += zv.z * wkv; ak[3] += zv.w * wkv;
      av[0] += zv.x * wvv; av[1] += zv.y * wvv; av[2] += zv.z * wvv; av[3] += zv.w * wvv;
    }
#pragma unroll
    for (int i = 0; i < 4; i++) {
      Qh[cg * 4 + i][d] = aq[i];
      Kh[cg * 4 + i][d] = ak[i];
      Vh[cg * 4 + i][d] = av[i];
    }
    __syncthreads();
    // scores: element (cS = cg + 8i, e = d)
    {
      float sacc[4] = {0, 0, 0, 0};
      const float4* KhR = (const float4*)&Kh[d][0];
#pragma unroll
      for (int d4 = 0; d4 < 8; d4++) {
        float4 kv = KhR[d4];
#pragma unroll
        for (int i = 0; i < 4; i++) {
          float4 qv = *(const float4*)&Qh[cg + 8 * i][d4 * 4];
          sacc[i] += qv.x * kv.x + qv.y * kv.y + qv.z * kv.z + qv.w * kv.w;
        }
      }
#pragma unroll
      for (int i = 0; i < 4; i++) {
        int cS = cg + 8 * i;
        float a = sacc[i] * scale;
        float mk = mask[bp * 1024 + cS * 32 + d];
        float smv = (mk > 0.5f) ? a : -1e9f;
        am[i] += a; mm[i] += smv;
        Sm[cS][d] = smv;
      }
    }
    __syncthreads();
    if (tid < 32) {
      float mx = -1e30f;
      for (int e = 0; e < 32; e++) mx = fmaxf(mx, Sm[tid][e]);
      float sum = 0.f;
      for (int e = 0; e < 32; e++) { float ev = expf(Sm[tid][e] - mx); Sm[tid][e] = ev; sum += ev; }
      float inv = 1.0f / sum;
      for (int e = 0; e < 32; e++) Sm[tid][e] *= inv;
    }
    __syncthreads();
#pragma unroll
    for (int i = 0; i < 4; i++) {
      int cA = cg * 4 + i;
      float acc = 0.f;
      for (int e = 0; e < 32; e++) acc += Sm[cA][e] * Vh[e][d];
      int gi = (bp * 32 + cA) * 256 + h * 32 + d;
      ao[gi] = acc + z[gi];
    }
    __syncthreads();
  }
#pragma unroll
  for (int i = 0; i < 4; i++) {
    int o = tid + i * 256;
    out4[bp * 1024 + o] = am[i] * 0.125f;
    out5[bp * 1024 + o] = mm[i] * 0.125f;
  }
}

// ---------------- generic tiled f32 GEMM: out = act(A@W + bias) (+res) ----------------
template <int ACT, bool RES>
__global__ __launch_bounds__(256) void gemm_kernel(const float* __restrict__ A,
    const float* __restrict__ W, const float* __restrict__ bias,
    const float* __restrict__ res, float* __restrict__ out, int K, int N) {
  __shared__ float As[16][68];
  __shared__ float Ws[16][68];
  int tid = threadIdx.x;
  int bm = blockIdx.x, bn = blockIdx.y;
  int tx = tid & 15, ty = tid >> 4;
  float acc[4][4] = {};
  int arow = tid >> 2, acol = (tid & 3) * 4;
  int wrow = tid >> 6, wcol = tid & 63;
  for (int kt = 0; kt < K; kt += 16) {
    {
      float4 v = *(const float4*)&A[(size_t)(bm * 64 + arow) * K + kt + acol];
      As[acol + 0][arow] = v.x; As[acol + 1][arow] = v.y;
      As[acol + 2][arow] = v.z; As[acol + 3][arow] = v.w;
    }
#pragma unroll
    for (int i = 0; i < 4; i++) {
      int wkk = wrow + i * 4;
      Ws[wkk][wcol] = W[(size_t)(kt + wkk) * N + bn * 64 + wcol];
    }
    __syncthreads();
#pragma unroll
    for (int k = 0; k < 16; k++) {
      float a[4], w[4];
#pragma unroll
      for (int i = 0; i < 4; i++) a[i] = As[k][ty * 4 + i];
#pragma unroll
      for (int j = 0; j < 4; j++) w[j] = Ws[k][tx * 4 + j];
#pragma unroll
      for (int i = 0; i < 4; i++)
#pragma unroll
        for (int j = 0; j < 4; j++) acc[i][j] += a[i] * w[j];
    }
    __syncthreads();
  }
#pragma unroll
  for (int i = 0; i < 4; i++) {
    int r = bm * 64 + ty * 4 + i;
#pragma unroll
    for (int j = 0; j < 4; j++) {
      int cc = bn * 64 + tx * 4 + j;
      float v = acc[i][j] + bias[cc];
      if (ACT == 2) v = 0.5f * v * (1.0f + erff(v * 0.70710678118654752f));
      if (RES) v += res[(size_t)r * N + cc];
      out[(size_t)r * N + cc] = v;
    }
  }
}

// ---------------- split z -> zr, zi ----------------
__global__ __launch_bounds__(256) void zsplit_kernel(const float* __restrict__ z,
    float* __restrict__ zr, float* __restrict__ zi) {
  int idx = blockIdx.x * 256 + threadIdx.x;  // over 512*16256
  int dd = idx & 127;
  int t = idx >> 7;
  int p = t % 127;
  int bc = t / 127;
  int b = bc >> 5, c = bc & 31;
  int src = ((b * 127 + p) * 32 + c) * 256 + dd;
  zr[idx] = z[src];
  zi[idx] = z[src + 128];
}

// ---------------- inverse FFT + transposed outputs ----------------
__global__ __launch_bounds__(256) void ifft_kernel(const float* __restrict__ xrr,
    const float* __restrict__ xir, float* __restrict__ out0,
    float* __restrict__ out1, float* __restrict__ out2) {
  __shared__ float re[1024], im[1024];
  __shared__ float tw[512][2];
  int tid = threadIdx.x, row = blockIdx.x;
  int b = row >> 5, c = row & 31;
  for (int k = tid; k < 512; k += 256) {
    double a = 2.0 * PI_ * (double)k / 1024.0;  // inverse sign
    tw[k][0] = (float)cos(a); tw[k][1] = (float)sin(a);
  }
  for (int l = tid; l < 1024; l += 256) {
    float vr = xrr[row * 1024 + l], vi = xir[row * 1024 + l];
    re[l] = vr; im[l] = vi;
    out1[(b * 1024 + l) * 32 + c] = vr;
    out2[(b * 1024 + l) * 32 + c] = vi;
  }
  __syncthreads();
  for (int i = tid; i < 1024; i += 256) {
    int j = __brev(i) >> 22;
    if (j > i) { float t = re[i]; re[i] = re[j]; re[j] = t; t = im[i]; im[i] = im[j]; im[j] = t; }
  }
  __syncthreads();
  for (int st = 0; st < 10; st++) {
    int half = 1 << st, tstep = 512 >> st;
    for (int bf = tid; bf < 512; bf += 256) {
      int grp = bf >> st, pos = bf & (half - 1);
      int i0 = (grp << (st + 1)) + pos, i1 = i0 + half;
      float wr = tw[pos * tstep][0], wi = tw[pos * tstep][1];
      float ar = re[i1], ai = im[i1];
      float tr = wr * ar - wi * ai, ti = wr * ai + wi * ar;
      re[i1] = re[i0] - tr; im[i1] = im[i0] - ti;
      re[i0] += tr; im[i0] += ti;
    }
    __syncthreads();
  }
  const float invN = 1.0f / 1024.0f;
  for (int l = tid; l < 1024; l += 256)
    out0[(b * 1024 + l) * 32 + c] = re[l] * invN;
}

// ---------------- host ----------------
extern "C" void kernel_launch(void* const* d_in, const int* in_sizes, int n_in,
                              void* d_out, int out_size, void* d_ws, size_t ws_size,
                              hipStream_t stream) {
  const float* x      = (const float*)d_in[0];
  const float* in_w   = (const float*)d_in[1];
  const float* in_b   = (const float*)d_in[2];
  const float* proj_w = (const float*)d_in[3];
  const float* proj_b = (const float*)d_in[4];
  const float* mg_w1  = (const float*)d_in[5];
  const float* mg_b1  = (const float*)d_in[6];
  const float* mg_w2  = (const float*)d_in[7];
  const float* mg_b2  = (const float*)d_in[8];
  const float* ln_w   = (const float*)d_in[9];
  const float* ln_b   = (const float*)d_in[10];
  const float* wq     = (const float*)d_in[11];
  const float* bq     = (const float*)d_in[12];
  const float* wk     = (const float*)d_in[13];
  const float* bk     = (const float*)d_in[14];
  const float* wv     = (const float*)d_in[15];
  const float* bv     = (const float*)d_in[16];
  const float* ffn_w1 = (const float*)d_in[17];
  const float* ffn_b1 = (const float*)d_in[18];
  const float* ffn_w2 = (const float*)d_in[19];
  const float* ffn_b2 = (const float*)d_in[20];
  const float* pr_w   = (const float*)d_in[21];
  const float* pr_b   = (const float*)d_in[22];
  const float* pi_w   = (const float*)d_in[23];
  const float* pi_b   = (const float*)d_in[24];
  float* out = (float*)d_out;

  char* wsp = (char*)d_ws;
  size_t off = 0;
  auto alloc = [&](size_t bytes) -> void* {
    void* p = wsp + off;
    off += (bytes + 255) & ~(size_t)255;
    return p;
  };
  double* xr64  = (double*)alloc(524288ull * 8);
  double* xi64  = (double*)alloc(524288ull * 8);
  float*  z     = (float*)alloc(16646144ull * 4);
  float*  ao    = (float*)alloc(16646144ull * 4);
  float*  maskb = (float*)alloc(2080768ull * 4);
  double* w2m   = (double*)alloc(8192ull * 8);
  double* b2m   = (double*)alloc(32ull * 8);
  float*  hidden= (float*)alloc(8323072ull * 4);
  float*  zr    = (float*)alloc(8323072ull * 4);
  float*  zi    = (float*)alloc(8323072ull * 4);
  float*  xrr   = (float*)alloc(524288ull * 4);
  float*  xir   = (float*)alloc(524288ull * 4);
  if (ws_size < off) return;  // insufficient workspace -> fail loudly

  // fold_in(key(42), l): key=(0,42), count=[0,l]
  uint32_t fk0[2], fk1[2];
  for (int l = 0; l < 2; l++) {
    uint32_t a, b;
    tf2x32(0u, 42u, 0u, (uint32_t)l, a, b);
    fk0[l] = a; fk1[l] = b;
  }

  ln_fft_kernel<<<512, 256, 0, stream>>>(x, in_w, in_b, xr64, xi64);
  patch_proj_kernel<<<2032, 256, 0, stream>>>(xr64, xi64, proj_w, proj_b, z);

  float* O3 = out + 1572864;
  float* O4 = out + 5734400;
  float* O5 = out + 9895936;
  for (int l = 0; l < 2; l++) {
    w2m_kernel<<<33, 256, 0, stream>>>(mg_w2 + l * 262144, mg_b2 + l * 1024, w2m, b2m);
    mask_kernel<<<2032, 256, 0, stream>>>(z, mg_w1 + l * 65536, mg_b1 + l * 256, w2m, b2m,
                                          fk0[l], fk1[l], maskb, O3 + l * 2080768);
    attn_kernel<<<2032, 256, 0, stream>>>(z, ln_w + l * 256, ln_b + l * 256,
                                          wq + l * 65536, bq + l * 256,
                                          wk + l * 65536, bk + l * 256,
                                          wv + l * 65536, bv + l * 256,
                                          maskb, ao, O4 + l * 2080768, O5 + l * 2080768);
    for (int ch = 0; ch < 8; ch++) {
      const float* Ain = ao + (size_t)ch * 8128 * 256;
      float* Zout = z + (size_t)ch * 8128 * 256;
      gemm_kernel<2, false><<<dim3(127, 16), 256, 0, stream>>>(
          Ain, ffn_w1 + l * 262144, ffn_b1 + l * 1024, nullptr, hidden, 256, 1024);
      gemm_kernel<0, true><<<dim3(127, 4), 256, 0, stream>>>(
          hidden, ffn_w2 + l * 262144, ffn_b2 + l * 256, Ain, Zout, 1024, 256);
    }
  }
  zsplit_kernel<<<32512, 256, 0, stream>>>(z, zr, zi);
  gemm_kernel<0, false><<<dim3(8, 16), 256, 0, stream>>>(zr, pr_w, pr_b, nullptr, xrr, 16256, 1024);
  gemm_kernel<0, false><<<dim3(8, 16), 256, 0, stream>>>(zi, pi_w, pi_b, nullptr, xir, 16256, 1024);
  ifft_kernel<<<512, 256, 0, stream>>>(xrr, xir, out, out + 524288, out + 1048576);
}

// Round 3
// 4762.856 us; speedup vs baseline: 1.8750x; 1.8750x over previous
//
#include <hip/hip_runtime.h>
#include <math.h>
#include <stdint.h>

#define PI_ 3.14159265358979323846

// ---------------- threefry2x32 (JAX-compatible) ----------------
__host__ __device__ inline void tf2x32(uint32_t k0, uint32_t k1, uint32_t x0, uint32_t x1,
                                       uint32_t& o0, uint32_t& o1) {
  uint32_t k2 = k0 ^ k1 ^ 0x1BD11BDAu;
  uint32_t v0 = x0 + k0, v1 = x1 + k1;
#define TF_R(r) { v0 += v1; v1 = ((v1 << (r)) | (v1 >> (32 - (r)))); v1 ^= v0; }
  TF_R(13) TF_R(15) TF_R(26) TF_R(6)
  v0 += k1; v1 += k2 + 1u;
  TF_R(17) TF_R(29) TF_R(16) TF_R(24)
  v0 += k2; v1 += k0 + 2u;
  TF_R(13) TF_R(15) TF_R(26) TF_R(6)
  v0 += k0; v1 += k1 + 3u;
  TF_R(17) TF_R(29) TF_R(16) TF_R(24)
  v0 += k1; v1 += k2 + 4u;
  TF_R(13) TF_R(15) TF_R(26) TF_R(6)
  v0 += k2; v1 += k0 + 5u;
#undef TF_R
  o0 = v0; o1 = v1;
}

// ---------------- LN over L + forward FFT(1024), f64 ----------------
__global__ __launch_bounds__(256) void ln_fft_kernel(const float* __restrict__ x,
    const float* __restrict__ in_w, const float* __restrict__ in_b,
    double* __restrict__ xr, double* __restrict__ xi) {
  __shared__ double re[1024], im[1024];
  __shared__ double tw[512][2];
  __shared__ double red[256];
  int tid = threadIdx.x, row = blockIdx.x;
  int b = row >> 5, c = row & 31;
  for (int k = tid; k < 512; k += 256) {
    double a = -2.0 * PI_ * (double)k / 1024.0;
    tw[k][0] = cos(a); tw[k][1] = sin(a);
  }
  double s = 0.0;
  for (int l = tid; l < 1024; l += 256) {
    double v = (double)x[(b * 1024 + l) * 32 + c];
    re[l] = v; s += v;
  }
  red[tid] = s; __syncthreads();
  for (int o = 128; o > 0; o >>= 1) { if (tid < o) red[tid] += red[tid + o]; __syncthreads(); }
  double mean = red[0] / 1024.0;
  __syncthreads();
  double s2 = 0.0;
  for (int l = tid; l < 1024; l += 256) { double d = re[l] - mean; s2 += d * d; }
  red[tid] = s2; __syncthreads();
  for (int o = 128; o > 0; o >>= 1) { if (tid < o) red[tid] += red[tid + o]; __syncthreads(); }
  double var = red[0] / 1024.0;
  double scl = (double)in_w[c] / sqrt(var + 1e-5);
  double shf = (double)in_b[c];
  __syncthreads();
  for (int l = tid; l < 1024; l += 256) { re[l] = (re[l] - mean) * scl + shf; im[l] = 0.0; }
  __syncthreads();
  for (int i = tid; i < 1024; i += 256) {
    int j = __brev(i) >> 22;
    if (j > i) { double t = re[i]; re[i] = re[j]; re[j] = t; t = im[i]; im[i] = im[j]; im[j] = t; }
  }
  __syncthreads();
  for (int st = 0; st < 10; st++) {
    int half = 1 << st, tstep = 512 >> st;
    for (int bf = tid; bf < 512; bf += 256) {
      int grp = bf >> st, pos = bf & (half - 1);
      int i0 = (grp << (st + 1)) + pos, i1 = i0 + half;
      double wr = tw[pos * tstep][0], wi = tw[pos * tstep][1];
      double ar = re[i1], ai = im[i1];
      double tr = wr * ar - wi * ai, ti = wr * ai + wi * ar;
      re[i1] = re[i0] - tr; im[i1] = im[i0] - ti;
      re[i0] += tr; im[i0] += ti;
    }
    __syncthreads();
  }
  for (int l = tid; l < 1024; l += 256) { xr[row * 1024 + l] = re[l]; xi[row * 1024 + l] = im[l]; }
}

// ---------------- patches -> z (f64 accum, f32 store) ----------------
__global__ __launch_bounds__(256) void patch_proj_kernel(const double* __restrict__ xr,
    const double* __restrict__ xi, const float* __restrict__ proj_w,
    const float* __restrict__ proj_b, float* __restrict__ z) {
  __shared__ double pr[32][16], pi[32][16];
  __shared__ float pw[32][256];
  int tid = threadIdx.x, bp = blockIdx.x;
  int b = bp / 127, p = bp % 127;
  for (int t = tid; t < 512; t += 256) {
    int c = t >> 4, q = t & 15;
    pr[c][q] = xr[(b * 32 + c) * 1024 + p * 8 + q];
    pi[c][q] = xi[(b * 32 + c) * 1024 + p * 8 + q];
  }
  for (int t = tid; t < 8192; t += 256) pw[t >> 8][t & 255] = proj_w[t];
  __syncthreads();
  int h = tid;
  for (int c = 0; c < 32; c++) {
    double acc = (double)proj_b[h];
#pragma unroll
    for (int q = 0; q < 16; q++)
      acc += pr[c][q] * (double)pw[q][h] + pi[c][q] * (double)pw[16 + q][h];
    z[(bp * 32 + c) * 256 + h] = (float)acc;
  }
}

// ---------------- fold mg_w2 mean over last C ----------------
__global__ __launch_bounds__(256) void w2m_kernel(const float* __restrict__ mg_w2,
    const float* __restrict__ mg_b2, double* __restrict__ w2m, double* __restrict__ b2m) {
  int t = blockIdx.x * 256 + threadIdx.x;
  if (t < 8192) {
    int k = t >> 5, e = t & 31;
    double s = 0.0;
    for (int j = 0; j < 32; j++) s += (double)mg_w2[k * 1024 + e * 32 + j];
    w2m[k * 32 + e] = s / 32.0;
  } else if (t < 8224) {
    int e = t - 8192;
    double s = 0.0;
    for (int j = 0; j < 32; j++) s += (double)mg_b2[e * 32 + j];
    b2m[e] = s / 32.0;
  }
}

// ---------------- mask gate (chunk of bp): h1(f64) -> logits -> gumbel ----------------
__global__ __launch_bounds__(256) void mask_kernel(const float* __restrict__ z,
    const float* __restrict__ w1, const float* __restrict__ b1,
    const double* __restrict__ w2m, const double* __restrict__ b2m,
    uint32_t fk0, uint32_t fk1, int bp0,
    float* __restrict__ mask, float* __restrict__ out3) {
  __shared__ float ztT[256][32];
  __shared__ float h1[32][256];
  int tid = threadIdx.x, bpl = blockIdx.x;
  {
    int c = tid >> 3, k0 = (tid & 7) * 32;
    const float* zp = z + (bpl * 32 + c) * 256 + k0;
    for (int i = 0; i < 32; i++) ztT[k0 + i][c] = zp[i];
  }
  __syncthreads();
  {
    double acc[32];
    double bb = (double)b1[tid];
#pragma unroll
    for (int c = 0; c < 32; c++) acc[c] = bb;
    for (int k = 0; k < 256; k++) {
      double wv = (double)w1[k * 256 + tid];
      const float4* z4 = (const float4*)&ztT[k][0];
#pragma unroll
      for (int j = 0; j < 8; j++) {
        float4 v = z4[j];
        acc[j * 4 + 0] += (double)v.x * wv;
        acc[j * 4 + 1] += (double)v.y * wv;
        acc[j * 4 + 2] += (double)v.z * wv;
        acc[j * 4 + 3] += (double)v.w * wv;
      }
    }
#pragma unroll
    for (int c = 0; c < 32; c++) h1[c][tid] = (float)fmax(acc[c], 0.0);
  }
  __syncthreads();
  for (int i = 0; i < 4; i++) {
    int o = tid + i * 256;
    int c = o >> 5, e = o & 31;
    double acc = b2m[e];
    for (int k = 0; k < 256; k++) acc += (double)h1[c][k] * w2m[k * 32 + e];
    float logit = (float)acc;
    float prob = (float)(1.0 / (1.0 + exp(-(double)logit)));
    unsigned gidx = (unsigned)(bp0 + bpl) * 1024u + (unsigned)o;
    uint32_t o0, o1;
    tf2x32(fk0, fk1, 0u, gidx, o0, o1);
    uint32_t bits = o0 ^ o1;
    float u = __uint_as_float((bits >> 9) | 0x3f800000u) - 1.0f;
    float t0 = u + 1e-10f;
    float l0 = (float)log((double)t0);
    float t1 = -l0 + 1e-10f;
    float g = -(float)log((double)t1);
    float sarg = prob + g;
    float ys = (float)(1.0 / (1.0 + exp(-(double)sarg)));
    float mv = (c == e || ys > 0.5f) ? 1.0f : 0.0f;
    mask[bpl * 1024 + o] = mv;
    out3[gidx] = mv;
  }
}

// ---------------- per-row LN stats (mean, rstd) ----------------
__global__ __launch_bounds__(256) void lnstats_kernel(const float* __restrict__ z,
                                                      float2* __restrict__ stats) {
  int wave = threadIdx.x >> 6, lane = threadIdx.x & 63;
  int row = blockIdx.x * 4 + wave;
  float4 v = *(const float4*)&z[(size_t)row * 256 + lane * 4];
  float s = v.x + v.y + v.z + v.w;
  for (int o = 32; o > 0; o >>= 1) s += __shfl_down(s, o, 64);
  s = __shfl(s, 0, 64);
  float mean = s * (1.0f / 256.0f);
  float dx = v.x - mean, dy = v.y - mean, dz = v.z - mean, dw = v.w - mean;
  float s2 = dx * dx + dy * dy + dz * dz + dw * dw;
  for (int o = 32; o > 0; o >>= 1) s2 += __shfl_down(s2, o, 64);
  if (lane == 0) stats[row] = make_float2(mean, 1.0f / sqrtf(s2 * (1.0f / 256.0f) + 1e-5f));
}

// ---------------- 128x128x16 f32 GEMM, 8x8 micro-tile ----------------
// MODE 0: QKV  — A=z w/ fused LN, B selected by bn>>1 (wq/wk/wv), permuted store
// MODE 1: FFN1 — plain A, GELU epilogue
// MODE 2: FFN2 — plain A, +bias +residual
// MODE 3: final proj — A gathered from z (r/i split), split-K over grid.z
template <int MODE>
__global__ __launch_bounds__(256) void gemm128(
    const float* __restrict__ A,
    const float* __restrict__ B0, const float* __restrict__ B1, const float* __restrict__ B2,
    const float* __restrict__ bias0, const float* __restrict__ bias1, const float* __restrict__ bias2,
    const float2* __restrict__ stats, const float* __restrict__ lnw, const float* __restrict__ lnb,
    const float* __restrict__ res,
    float* __restrict__ out0, float* __restrict__ out1, float* __restrict__ out2,
    int Mrows, int Kdim, int Ndim) {
  __shared__ float As[16][132];
  __shared__ float Bs[16][132];
  const int tid = threadIdx.x;
  const int tx = tid & 15, ty = tid >> 4;
  const int bm = blockIdx.x, bn = blockIdx.y;
  const int m0 = bm * 128;

  const float* Bp = B0;
  const float* biasp = bias0;
  float* outsel = out0;
  int n0 = bn * 128;
  int kstart = 0;
  int Keff = Kdim;
  int imag = 0;
  if constexpr (MODE == 0) {
    int sel = bn >> 1;
    Bp = sel == 0 ? B0 : (sel == 1 ? B1 : B2);
    biasp = sel == 0 ? bias0 : (sel == 1 ? bias1 : bias2);
    outsel = sel == 0 ? out0 : (sel == 1 ? out1 : out2);
    n0 = (bn & 1) * 128;
  }
  if constexpr (MODE == 3) {
    imag = (blockIdx.z >= 8) ? 1 : 0;
    kstart = (int)(blockIdx.z & 7) * 2032;
    Bp = imag ? B1 : B0;
    outsel = out0 + (size_t)blockIdx.z * 524288;
    Keff = 2032;
  }

  const int arow = tid >> 2;       // 0..63 (and +64)
  const int kq = (tid & 3) * 4;    // 0,4,8,12
  float2 st0, st1;
  if constexpr (MODE == 0) { st0 = stats[m0 + arow]; st1 = stats[m0 + arow + 64]; }
  const int brow = tid >> 5;       // 0..7 (and +8)
  const int bcol = (tid & 31) * 4; // 0..124

  float acc[8][8] = {};
  for (int kt = 0; kt < Keff; kt += 16) {
    float4 wa4, ba4;
    if constexpr (MODE == 0) {
      wa4 = *(const float4*)&lnw[kt + kq];
      ba4 = *(const float4*)&lnb[kt + kq];
    }
#pragma unroll
    for (int q = 0; q < 2; q++) {
      int ar = arow + q * 64;
      float4 v;
      if constexpr (MODE == 3) {
        int row = m0 + ar;
        int b = row >> 5, c = row & 31;
        int kg = kstart + kt + kq;
        int p = kg >> 7, dd = kg & 127;
        v = *(const float4*)&A[(size_t)((b * 127 + p) * 32 + c) * 256 + dd + imag * 128];
      } else {
        v = *(const float4*)&A[(size_t)(m0 + ar) * Kdim + kt + kq];
        if constexpr (MODE == 0) {
          float2 st = q ? st1 : st0;
          v.x = (v.x - st.x) * st.y * wa4.x + ba4.x;
          v.y = (v.y - st.x) * st.y * wa4.y + ba4.y;
          v.z = (v.z - st.x) * st.y * wa4.z + ba4.z;
          v.w = (v.w - st.x) * st.y * wa4.w + ba4.w;
        }
      }
      As[kq + 0][ar] = v.x; As[kq + 1][ar] = v.y;
      As[kq + 2][ar] = v.z; As[kq + 3][ar] = v.w;
    }
#pragma unroll
    for (int q = 0; q < 2; q++) {
      int br = brow + q * 8;
      *(float4*)&Bs[br][bcol] =
          *(const float4*)&Bp[(size_t)(kstart + kt + br) * Ndim + n0 + bcol];
    }
    __syncthreads();
#pragma unroll
    for (int k = 0; k < 16; k++) {
      float4 a0 = *(const float4*)&As[k][ty * 8];
      float4 a1 = *(const float4*)&As[k][ty * 8 + 4];
      float4 b0 = *(const float4*)&Bs[k][tx * 8];
      float4 b1 = *(const float4*)&Bs[k][tx * 8 + 4];
      float av[8] = {a0.x, a0.y, a0.z, a0.w, a1.x, a1.y, a1.z, a1.w};
      float bv[8] = {b0.x, b0.y, b0.z, b0.w, b1.x, b1.y, b1.z, b1.w};
#pragma unroll
      for (int i = 0; i < 8; i++)
#pragma unroll
        for (int j = 0; j < 8; j++) acc[i][j] += av[i] * bv[j];
    }
    __syncthreads();
  }

  const int col0 = n0 + tx * 8;
  if constexpr (MODE == 0) {
    int h = (col0 & 255) >> 5;
    int d0 = col0 & 31;
    float bb[8];
#pragma unroll
    for (int j = 0; j < 8; j++) bb[j] = biasp[col0 + j];
#pragma unroll
    for (int i = 0; i < 8; i++) {
      int r = m0 + ty * 8 + i;
      int bp = r >> 5, cc = r & 31;
      float* dst = outsel + (((size_t)(bp * 8 + h) * 32 + cc) * 32 + d0);
      *(float4*)dst = make_float4(acc[i][0] + bb[0], acc[i][1] + bb[1],
                                  acc[i][2] + bb[2], acc[i][3] + bb[3]);
      *(float4*)(dst + 4) = make_float4(acc[i][4] + bb[4], acc[i][5] + bb[5],
                                        acc[i][6] + bb[6], acc[i][7] + bb[7]);
    }
  } else if constexpr (MODE == 1) {
    float bb[8];
#pragma unroll
    for (int j = 0; j < 8; j++) bb[j] = bias0[col0 + j];
#pragma unroll
    for (int i = 0; i < 8; i++) {
      int r = m0 + ty * 8 + i;
      float vv[8];
#pragma unroll
      for (int j = 0; j < 8; j++) {
        float v = acc[i][j] + bb[j];
        vv[j] = 0.5f * v * (1.0f + erff(v * 0.70710678118654752f));
      }
      float* dst = out0 + (size_t)r * Ndim + col0;
      *(float4*)dst = make_float4(vv[0], vv[1], vv[2], vv[3]);
      *(float4*)(dst + 4) = make_float4(vv[4], vv[5], vv[6], vv[7]);
    }
  } else if constexpr (MODE == 2) {
    float bb[8];
#pragma unroll
    for (int j = 0; j < 8; j++) bb[j] = bias0[col0 + j];
#pragma unroll
    for (int i = 0; i < 8; i++) {
      int r = m0 + ty * 8 + i;
      const float* rp = res + (size_t)r * Ndim + col0;
      float4 r0 = *(const float4*)rp;
      float4 r1 = *(const float4*)(rp + 4);
      float* dst = out0 + (size_t)r * Ndim + col0;
      *(float4*)dst = make_float4(acc[i][0] + bb[0] + r0.x, acc[i][1] + bb[1] + r0.y,
                                  acc[i][2] + bb[2] + r0.z, acc[i][3] + bb[3] + r0.w);
      *(float4*)(dst + 4) = make_float4(acc[i][4] + bb[4] + r1.x, acc[i][5] + bb[5] + r1.y,
                                        acc[i][6] + bb[6] + r1.z, acc[i][7] + bb[7] + r1.w);
    }
  } else {  // MODE 3: raw partial store
#pragma unroll
    for (int i = 0; i < 8; i++) {
      int r = m0 + ty * 8 + i;
      float* dst = outsel + (size_t)r * 1024 + col0;
      *(float4*)dst = make_float4(acc[i][0], acc[i][1], acc[i][2], acc[i][3]);
      *(float4*)(dst + 4) = make_float4(acc[i][4], acc[i][5], acc[i][6], acc[i][7]);
    }
  }
}

// ---------------- lightweight masked attention (per bp in chunk) ----------------
__global__ __launch_bounds__(256) void attn2_kernel(const float* __restrict__ Qb,
    const float* __restrict__ Kb, const float* __restrict__ Vb,
    const float* __restrict__ mask, const float* __restrict__ z, float* __restrict__ ao,
    float* __restrict__ out4, float* __restrict__ out5) {
  __shared__ float Qs[32][33], Ks[32][33], Vs[32][33], Ps[32][33];
  __shared__ float mk[32][32];
  __shared__ float red[32][8];
  int tid = threadIdx.x, bp = blockIdx.x;
  {
    float4 v = ((const float4*)(mask + (size_t)bp * 1024))[tid];
    int c = tid >> 3, e0 = (tid & 7) * 4;
    mk[c][e0] = v.x; mk[c][e0 + 1] = v.y; mk[c][e0 + 2] = v.z; mk[c][e0 + 3] = v.w;
  }
  const int c = tid >> 3, g = tid & 7, e0 = g * 4;
  float am[4] = {0, 0, 0, 0}, mm[4] = {0, 0, 0, 0};
  const float scale = 0.17677669529663687f;
  for (int h = 0; h < 8; h++) {
    __syncthreads();
    {
      size_t base = ((size_t)(bp * 8 + h) << 10) + tid * 4;
      float4 q = *(const float4*)&Qb[base];
      float4 k = *(const float4*)&Kb[base];
      float4 v = *(const float4*)&Vb[base];
      int cc = tid >> 3, d0 = (tid & 7) * 4;
      Qs[cc][d0] = q.x; Qs[cc][d0 + 1] = q.y; Qs[cc][d0 + 2] = q.z; Qs[cc][d0 + 3] = q.w;
      Ks[cc][d0] = k.x; Ks[cc][d0 + 1] = k.y; Ks[cc][d0 + 2] = k.z; Ks[cc][d0 + 3] = k.w;
      Vs[cc][d0] = v.x; Vs[cc][d0 + 1] = v.y; Vs[cc][d0 + 2] = v.z; Vs[cc][d0 + 3] = v.w;
    }
    __syncthreads();
    float sv[4];
#pragma unroll
    for (int j = 0; j < 4; j++) {
      int e = e0 + j;
      float s = 0.f;
#pragma unroll
      for (int d = 0; d < 32; d += 4)
        s += Qs[c][d] * Ks[e][d] + Qs[c][d + 1] * Ks[e][d + 1] +
             Qs[c][d + 2] * Ks[e][d + 2] + Qs[c][d + 3] * Ks[e][d + 3];
      float a = s * scale;
      am[j] += a;
      float smv = (mk[c][e] > 0.5f) ? a : -1e9f;
      mm[j] += smv;
      sv[j] = smv;
    }
    red[c][g] = fmaxf(fmaxf(sv[0], sv[1]), fmaxf(sv[2], sv[3]));
    __syncthreads();
    float mx = red[c][0];
#pragma unroll
    for (int j = 1; j < 8; j++) mx = fmaxf(mx, red[c][j]);
    __syncthreads();
    float ev[4], ls = 0.f;
#pragma unroll
    for (int j = 0; j < 4; j++) { ev[j] = expf(sv[j] - mx); ls += ev[j]; }
    red[c][g] = ls;
    __syncthreads();
    float sum = 0.f;
#pragma unroll
    for (int j = 0; j < 8; j++) sum += red[c][j];
    float inv = 1.0f / sum;
#pragma unroll
    for (int j = 0; j < 4; j++) Ps[c][e0 + j] = ev[j] * inv;
    __syncthreads();
    {
      int d0 = (tid & 7) * 4;
      float o0 = 0, o1 = 0, o2 = 0, o3 = 0;
#pragma unroll
      for (int e = 0; e < 32; e++) {
        float p = Ps[c][e];
        o0 += p * Vs[e][d0]; o1 += p * Vs[e][d0 + 1];
        o2 += p * Vs[e][d0 + 2]; o3 += p * Vs[e][d0 + 3];
      }
      size_t gi = ((size_t)(bp * 32 + c)) * 256 + h * 32 + d0;
      float4 zr = *(const float4*)&z[gi];
      *(float4*)&ao[gi] = make_float4(o0 + zr.x, o1 + zr.y, o2 + zr.z, o3 + zr.w);
    }
  }
  size_t ob = (size_t)bp * 1024 + c * 32 + e0;
#pragma unroll
  for (int j = 0; j < 4; j++) {
    out4[ob + j] = am[j] * 0.125f;
    out5[ob + j] = mm[j] * 0.125f;
  }
}

// ---------------- split-K reduce + bias for final projection ----------------
__global__ __launch_bounds__(256) void reduce_kernel(const float* __restrict__ partial,
    const float* __restrict__ pr_b, const float* __restrict__ pi_b,
    float* __restrict__ xrr, float* __restrict__ xir) {
  int idx = blockIdx.x * 256 + threadIdx.x;  // 524288
  int l = idx & 1023;
  float s = 0.f;
  for (int k = 0; k < 8; k++) s += partial[(size_t)k * 524288 + idx];
  xrr[idx] = s + pr_b[l];
  float t = 0.f;
  for (int k = 8; k < 16; k++) t += partial[(size_t)k * 524288 + idx];
  xir[idx] = t + pi_b[l];
}

// ---------------- inverse FFT + transposed outputs ----------------
__global__ __launch_bounds__(256) void ifft_kernel(const float* __restrict__ xrr,
    const float* __restrict__ xir, float* __restrict__ out0,
    float* __restrict__ out1, float* __restrict__ out2) {
  __shared__ float re[1024], im[1024];
  __shared__ float tw[512][2];
  int tid = threadIdx.x, row = blockIdx.x;
  int b = row >> 5, c = row & 31;
  for (int k = tid; k < 512; k += 256) {
    double a = 2.0 * PI_ * (double)k / 1024.0;
    tw[k][0] = (float)cos(a); tw[k][1] = (float)sin(a);
  }
  for (int l = tid; l < 1024; l += 256) {
    float vr = xrr[row * 1024 + l], vi = xir[row * 1024 + l];
    re[l] = vr; im[l] = vi;
    out1[(b * 1024 + l) * 32 + c] = vr;
    out2[(b * 1024 + l) * 32 + c] = vi;
  }
  __syncthreads();
  for (int i = tid; i < 1024; i += 256) {
    int j = __brev(i) >> 22;
    if (j > i) { float t = re[i]; re[i] = re[j]; re[j] = t; t = im[i]; im[i] = im[j]; im[j] = t; }
  }
  __syncthreads();
  for (int st = 0; st < 10; st++) {
    int half = 1 << st, tstep = 512 >> st;
    for (int bf = tid; bf < 512; bf += 256) {
      int grp = bf >> st, pos = bf & (half - 1);
      int i0 = (grp << (st + 1)) + pos, i1 = i0 + half;
      float wr = tw[pos * tstep][0], wi = tw[pos * tstep][1];
      float ar = re[i1], ai = im[i1];
      float tr = wr * ar - wi * ai, ti = wr * ai + wi * ar;
      re[i1] = re[i0] - tr; im[i1] = im[i0] - ti;
      re[i0] += tr; im[i0] += ti;
    }
    __syncthreads();
  }
  const float invN = 1.0f / 1024.0f;
  for (int l = tid; l < 1024; l += 256)
    out0[(b * 1024 + l) * 32 + c] = re[l] * invN;
}

// ---------------- host ----------------
extern "C" void kernel_launch(void* const* d_in, const int* in_sizes, int n_in,
                              void* d_out, int out_size, void* d_ws, size_t ws_size,
                              hipStream_t stream) {
  const float* x      = (const float*)d_in[0];
  const float* in_w   = (const float*)d_in[1];
  const float* in_b   = (const float*)d_in[2];
  const float* proj_w = (const float*)d_in[3];
  const float* proj_b = (const float*)d_in[4];
  const float* mg_w1  = (const float*)d_in[5];
  const float* mg_b1  = (const float*)d_in[6];
  const float* mg_w2  = (const float*)d_in[7];
  const float* mg_b2  = (const float*)d_in[8];
  const float* ln_w   = (const float*)d_in[9];
  const float* ln_b   = (const float*)d_in[10];
  const float* wq     = (const float*)d_in[11];
  const float* bq     = (const float*)d_in[12];
  const float* wk     = (const float*)d_in[13];
  const float* bk     = (const float*)d_in[14];
  const float* wv     = (const float*)d_in[15];
  const float* bv     = (const float*)d_in[16];
  const float* ffn_w1 = (const float*)d_in[17];
  const float* ffn_b1 = (const float*)d_in[18];
  const float* ffn_w2 = (const float*)d_in[19];
  const float* ffn_b2 = (const float*)d_in[20];
  const float* pr_w   = (const float*)d_in[21];
  const float* pr_b   = (const float*)d_in[22];
  const float* pi_w   = (const float*)d_in[23];
  const float* pi_b   = (const float*)d_in[24];
  float* out = (float*)d_out;

  // Arena — per-chunk (508 bp = 16256 rows) layer pipeline. No aliasing within
  // a layer. Peak ~202 MB (< known-good 254 MB).
  //   z       66,584,576   persistent
  //   Qb/Kb/Vb 16,646,144 ×3  chunk QKV
  //   ao      16,646,144   chunk attn out
  //   hidden  66,584,576   chunk FFN hidden | (pre: xr64+xi64) | (post: partial+xrr+xir)
  //   maskb    2,080,768   chunk mask
  //   stats      130,048   chunk LN stats
  //   w2m/b2m     65,792
  char* wsp = (char*)d_ws;
  float*  z      = (float*)(wsp);
  float*  Qb     = (float*)(wsp + 66584576ull);
  float*  Kb     = (float*)(wsp + 66584576ull + 16646144ull);
  float*  Vb     = (float*)(wsp + 66584576ull + 2 * 16646144ull);
  float*  ao     = (float*)(wsp + 66584576ull + 3 * 16646144ull);
  char*   Hreg   = wsp + 66584576ull + 4 * 16646144ull;           // 66,584,576 bytes
  float*  hidden = (float*)Hreg;
  double* xr64   = (double*)Hreg;
  double* xi64   = (double*)(Hreg + 4194304ull);
  float*  partial= (float*)Hreg;                                   // 33,554,432
  float*  xrr    = (float*)(Hreg + 33554432ull);                   //  2,097,152
  float*  xir    = (float*)(Hreg + 33554432ull + 2097152ull);
  char*   Ereg   = wsp + 66584576ull + 4 * 16646144ull + 66584576ull;
  float*  maskb  = (float*)Ereg;
  float2* stats  = (float2*)(Ereg + 2080768ull);
  double* w2m    = (double*)(Ereg + 2080768ull + 130048ull);
  double* b2m    = (double*)(Ereg + 2080768ull + 130048ull + 65536ull);
  size_t need = 66584576ull + 4 * 16646144ull + 66584576ull + 2080768ull + 130048ull + 66048ull;
  if (ws_size < need) return;

  uint32_t fk0[2], fk1[2];
  for (int l = 0; l < 2; l++) {
    uint32_t a, b;
    tf2x32(0u, 42u, 0u, (uint32_t)l, a, b);
    fk0[l] = a; fk1[l] = b;
  }

  ln_fft_kernel<<<512, 256, 0, stream>>>(x, in_w, in_b, xr64, xi64);
  patch_proj_kernel<<<2032, 256, 0, stream>>>(xr64, xi64, proj_w, proj_b, z);

  float* O3 = out + 1572864;
  float* O4 = out + 5734400;
  float* O5 = out + 9895936;
  for (int l = 0; l < 2; l++) {
    w2m_kernel<<<33, 256, 0, stream>>>(mg_w2 + l * 262144, mg_b2 + l * 1024, w2m, b2m);
    for (int ch = 0; ch < 4; ch++) {
      int bp0 = ch * 508;
      float* zc = z + (size_t)bp0 * 8192;
      mask_kernel<<<508, 256, 0, stream>>>(zc, mg_w1 + l * 65536, mg_b1 + l * 256,
                                           w2m, b2m, fk0[l], fk1[l], bp0,
                                           maskb, O3 + l * 2080768);
      lnstats_kernel<<<4064, 256, 0, stream>>>(zc, stats);
      gemm128<0><<<dim3(127, 6), 256, 0, stream>>>(
          zc, wq + l * 65536, wk + l * 65536, wv + l * 65536,
          bq + l * 256, bk + l * 256, bv + l * 256,
          stats, ln_w + l * 256, ln_b + l * 256, nullptr,
          Qb, Kb, Vb, 16256, 256, 256);
      attn2_kernel<<<508, 256, 0, stream>>>(Qb, Kb, Vb, maskb, zc, ao,
                                            O4 + l * 2080768 + (size_t)bp0 * 1024,
                                            O5 + l * 2080768 + (size_t)bp0 * 1024);
      gemm128<1><<<dim3(127, 8), 256, 0, stream>>>(
          ao, ffn_w1 + l * 262144, nullptr, nullptr,
          ffn_b1 + l * 1024, nullptr, nullptr, nullptr, nullptr, nullptr, nullptr,
          hidden, nullptr, nullptr, 16256, 256, 1024);
      gemm128<2><<<dim3(127, 2), 256, 0, stream>>>(
          hidden, ffn_w2 + l * 262144, nullptr, nullptr,
          ffn_b2 + l * 256, nullptr, nullptr, nullptr, nullptr, nullptr,
          ao, zc, nullptr, nullptr, 16256, 1024, 256);
    }
  }
  gemm128<3><<<dim3(4, 8, 16), 256, 0, stream>>>(
      z, pr_w, pi_w, nullptr, nullptr, nullptr, nullptr, nullptr, nullptr, nullptr, nullptr,
      partial, nullptr, nullptr, 512, 16256, 1024);
  reduce_kernel<<<2048, 256, 0, stream>>>(partial, pr_b, pi_b, xrr, xir);
  ifft_kernel<<<512, 256, 0, stream>>>(xrr, xir, out, out + 524288, out + 1048576);
}

// Round 4
// 3696.552 us; speedup vs baseline: 2.4159x; 1.2885x over previous
//
#include <hip/hip_runtime.h>
#include <math.h>
#include <stdint.h>

#define PI_ 3.14159265358979323846

typedef __bf16 bf16_t;
typedef __attribute__((ext_vector_type(8))) __bf16 bf8v;
typedef __attribute__((ext_vector_type(4))) float f4v;

union BPack { bf8v v; bf16_t e[8]; uint4 u; };

// ---------------- threefry2x32 (JAX-compatible) ----------------
__host__ __device__ inline void tf2x32(uint32_t k0, uint32_t k1, uint32_t x0, uint32_t x1,
                                       uint32_t& o0, uint32_t& o1) {
  uint32_t k2 = k0 ^ k1 ^ 0x1BD11BDAu;
  uint32_t v0 = x0 + k0, v1 = x1 + k1;
#define TF_R(r) { v0 += v1; v1 = ((v1 << (r)) | (v1 >> (32 - (r)))); v1 ^= v0; }
  TF_R(13) TF_R(15) TF_R(26) TF_R(6)
  v0 += k1; v1 += k2 + 1u;
  TF_R(17) TF_R(29) TF_R(16) TF_R(24)
  v0 += k2; v1 += k0 + 2u;
  TF_R(13) TF_R(15) TF_R(26) TF_R(6)
  v0 += k0; v1 += k1 + 3u;
  TF_R(17) TF_R(29) TF_R(16) TF_R(24)
  v0 += k1; v1 += k2 + 4u;
  TF_R(13) TF_R(15) TF_R(26) TF_R(6)
  v0 += k2; v1 += k0 + 5u;
#undef TF_R
  o0 = v0; o1 = v1;
}

// ---------------- LN over L + forward FFT(1024), f64 ----------------
__global__ __launch_bounds__(256) void ln_fft_kernel(const float* __restrict__ x,
    const float* __restrict__ in_w, const float* __restrict__ in_b,
    double* __restrict__ xr, double* __restrict__ xi) {
  __shared__ double re[1024], im[1024];
  __shared__ double tw[512][2];
  __shared__ double red[256];
  int tid = threadIdx.x, row = blockIdx.x;
  int b = row >> 5, c = row & 31;
  for (int k = tid; k < 512; k += 256) {
    double a = -2.0 * PI_ * (double)k / 1024.0;
    tw[k][0] = cos(a); tw[k][1] = sin(a);
  }
  double s = 0.0;
  for (int l = tid; l < 1024; l += 256) {
    double v = (double)x[(b * 1024 + l) * 32 + c];
    re[l] = v; s += v;
  }
  red[tid] = s; __syncthreads();
  for (int o = 128; o > 0; o >>= 1) { if (tid < o) red[tid] += red[tid + o]; __syncthreads(); }
  double mean = red[0] / 1024.0;
  __syncthreads();
  double s2 = 0.0;
  for (int l = tid; l < 1024; l += 256) { double d = re[l] - mean; s2 += d * d; }
  red[tid] = s2; __syncthreads();
  for (int o = 128; o > 0; o >>= 1) { if (tid < o) red[tid] += red[tid + o]; __syncthreads(); }
  double var = red[0] / 1024.0;
  double scl = (double)in_w[c] / sqrt(var + 1e-5);
  double shf = (double)in_b[c];
  __syncthreads();
  for (int l = tid; l < 1024; l += 256) { re[l] = (re[l] - mean) * scl + shf; im[l] = 0.0; }
  __syncthreads();
  for (int i = tid; i < 1024; i += 256) {
    int j = __brev(i) >> 22;
    if (j > i) { double t = re[i]; re[i] = re[j]; re[j] = t; t = im[i]; im[i] = im[j]; im[j] = t; }
  }
  __syncthreads();
  for (int st = 0; st < 10; st++) {
    int half = 1 << st, tstep = 512 >> st;
    for (int bf = tid; bf < 512; bf += 256) {
      int grp = bf >> st, pos = bf & (half - 1);
      int i0 = (grp << (st + 1)) + pos, i1 = i0 + half;
      double wr = tw[pos * tstep][0], wi = tw[pos * tstep][1];
      double ar = re[i1], ai = im[i1];
      double tr = wr * ar - wi * ai, ti = wr * ai + wi * ar;
      re[i1] = re[i0] - tr; im[i1] = im[i0] - ti;
      re[i0] += tr; im[i0] += ti;
    }
    __syncthreads();
  }
  for (int l = tid; l < 1024; l += 256) { xr[row * 1024 + l] = re[l]; xi[row * 1024 + l] = im[l]; }
}

// ---------------- patches -> z (f64 accum, f32 store) ----------------
__global__ __launch_bounds__(256) void patch_proj_kernel(const double* __restrict__ xr,
    const double* __restrict__ xi, const float* __restrict__ proj_w,
    const float* __restrict__ proj_b, float* __restrict__ z) {
  __shared__ double pr[32][16], pi[32][16];
  __shared__ float pw[32][256];
  int tid = threadIdx.x, bp = blockIdx.x;
  int b = bp / 127, p = bp % 127;
  for (int t = tid; t < 512; t += 256) {
    int c = t >> 4, q = t & 15;
    pr[c][q] = xr[(b * 32 + c) * 1024 + p * 8 + q];
    pi[c][q] = xi[(b * 32 + c) * 1024 + p * 8 + q];
  }
  for (int t = tid; t < 8192; t += 256) pw[t >> 8][t & 255] = proj_w[t];
  __syncthreads();
  int h = tid;
  for (int c = 0; c < 32; c++) {
    double acc = (double)proj_b[h];
#pragma unroll
    for (int q = 0; q < 16; q++)
      acc += pr[c][q] * (double)pw[q][h] + pi[c][q] * (double)pw[16 + q][h];
    z[(bp * 32 + c) * 256 + h] = (float)acc;
  }
}

// ---------------- fold mg_w2 mean over last C ----------------
__global__ __launch_bounds__(256) void w2m_kernel(const float* __restrict__ mg_w2,
    const float* __restrict__ mg_b2, double* __restrict__ w2m, double* __restrict__ b2m) {
  int t = blockIdx.x * 256 + threadIdx.x;
  if (t < 8192) {
    int k = t >> 5, e = t & 31;
    double s = 0.0;
    for (int j = 0; j < 32; j++) s += (double)mg_w2[k * 1024 + e * 32 + j];
    w2m[k * 32 + e] = s / 32.0;
  } else if (t < 8224) {
    int e = t - 8192;
    double s = 0.0;
    for (int j = 0; j < 32; j++) s += (double)mg_b2[e * 32 + j];
    b2m[e] = s / 32.0;
  }
}

// ---------------- mask gate (chunk of bp): h1(f64) -> logits -> gumbel ----------------
__global__ __launch_bounds__(256) void mask_kernel(const float* __restrict__ z,
    const float* __restrict__ w1, const float* __restrict__ b1,
    const double* __restrict__ w2m, const double* __restrict__ b2m,
    uint32_t fk0, uint32_t fk1, int bp0,
    float* __restrict__ mask, float* __restrict__ out3) {
  __shared__ float ztT[256][32];
  __shared__ float h1[32][256];
  int tid = threadIdx.x, bpl = blockIdx.x;
  {
    int c = tid >> 3, k0 = (tid & 7) * 32;
    const float* zp = z + (bpl * 32 + c) * 256 + k0;
    for (int i = 0; i < 32; i++) ztT[k0 + i][c] = zp[i];
  }
  __syncthreads();
  {
    double acc[32];
    double bb = (double)b1[tid];
#pragma unroll
    for (int c = 0; c < 32; c++) acc[c] = bb;
    for (int k = 0; k < 256; k++) {
      double wv = (double)w1[k * 256 + tid];
      const float4* z4 = (const float4*)&ztT[k][0];
#pragma unroll
      for (int j = 0; j < 8; j++) {
        float4 v = z4[j];
        acc[j * 4 + 0] += (double)v.x * wv;
        acc[j * 4 + 1] += (double)v.y * wv;
        acc[j * 4 + 2] += (double)v.z * wv;
        acc[j * 4 + 3] += (double)v.w * wv;
      }
    }
#pragma unroll
    for (int c = 0; c < 32; c++) h1[c][tid] = (float)fmax(acc[c], 0.0);
  }
  __syncthreads();
  for (int i = 0; i < 4; i++) {
    int o = tid + i * 256;
    int c = o >> 5, e = o & 31;
    double acc = b2m[e];
    for (int k = 0; k < 256; k++) acc += (double)h1[c][k] * w2m[k * 32 + e];
    float logit = (float)acc;
    float prob = (float)(1.0 / (1.0 + exp(-(double)logit)));
    unsigned gidx = (unsigned)(bp0 + bpl) * 1024u + (unsigned)o;
    uint32_t o0, o1;
    tf2x32(fk0, fk1, 0u, gidx, o0, o1);
    uint32_t bits = o0 ^ o1;
    float u = __uint_as_float((bits >> 9) | 0x3f800000u) - 1.0f;
    float t0 = u + 1e-10f;
    float l0 = (float)log((double)t0);
    float t1 = -l0 + 1e-10f;
    float g = -(float)log((double)t1);
    float sarg = prob + g;
    float ys = (float)(1.0 / (1.0 + exp(-(double)sarg)));
    float mv = (c == e || ys > 0.5f) ? 1.0f : 0.0f;
    mask[bpl * 1024 + o] = mv;
    out3[gidx] = mv;
  }
}

// ---------------- per-row LN stats (mean, rstd) ----------------
__global__ __launch_bounds__(256) void lnstats_kernel(const float* __restrict__ z,
                                                      float2* __restrict__ stats) {
  int wave = threadIdx.x >> 6, lane = threadIdx.x & 63;
  int row = blockIdx.x * 4 + wave;
  float4 v = *(const float4*)&z[(size_t)row * 256 + lane * 4];
  float s = v.x + v.y + v.z + v.w;
  for (int o = 32; o > 0; o >>= 1) s += __shfl_down(s, o, 64);
  s = __shfl(s, 0, 64);
  float mean = s * (1.0f / 256.0f);
  float dx = v.x - mean, dy = v.y - mean, dz = v.z - mean, dw = v.w - mean;
  float s2 = dx * dx + dy * dy + dz * dz + dw * dw;
  for (int o = 32; o > 0; o >>= 1) s2 += __shfl_down(s2, o, 64);
  if (lane == 0) stats[row] = make_float2(mean, 1.0f / sqrtf(s2 * (1.0f / 256.0f) + 1e-5f));
}

// ---------------- f32 128x128x16 GEMM (layer 0 only — feeds the mask path) ----------------
// MODE 0: QKV fused-LN, permuted store; MODE 1: FFN1 +GELU; MODE 2: FFN2 +bias+res
template <int MODE>
__global__ __launch_bounds__(256) void gemm128(
    const float* __restrict__ A,
    const float* __restrict__ B0, const float* __restrict__ B1, const float* __restrict__ B2,
    const float* __restrict__ bias0, const float* __restrict__ bias1, const float* __restrict__ bias2,
    const float2* __restrict__ stats, const float* __restrict__ lnw, const float* __restrict__ lnb,
    const float* __restrict__ res,
    float* __restrict__ out0, float* __restrict__ out1, float* __restrict__ out2,
    int Kdim, int Ndim) {
  __shared__ float As[16][132];
  __shared__ float Bs[16][132];
  const int tid = threadIdx.x;
  const int tx = tid & 15, ty = tid >> 4;
  const int bm = blockIdx.x, bn = blockIdx.y;
  const int m0 = bm * 128;

  const float* Bp = B0;
  const float* biasp = bias0;
  float* outsel = out0;
  int n0 = bn * 128;
  if constexpr (MODE == 0) {
    int sel = bn >> 1;
    Bp = sel == 0 ? B0 : (sel == 1 ? B1 : B2);
    biasp = sel == 0 ? bias0 : (sel == 1 ? bias1 : bias2);
    outsel = sel == 0 ? out0 : (sel == 1 ? out1 : out2);
    n0 = (bn & 1) * 128;
  }

  const int arow = tid >> 2;
  const int kq = (tid & 3) * 4;
  float2 st0, st1;
  if constexpr (MODE == 0) { st0 = stats[m0 + arow]; st1 = stats[m0 + arow + 64]; }
  const int brow = tid >> 5;
  const int bcol = (tid & 31) * 4;

  float acc[8][8] = {};
  for (int kt = 0; kt < Kdim; kt += 16) {
    float4 wa4, ba4;
    if constexpr (MODE == 0) {
      wa4 = *(const float4*)&lnw[kt + kq];
      ba4 = *(const float4*)&lnb[kt + kq];
    }
#pragma unroll
    for (int q = 0; q < 2; q++) {
      int ar = arow + q * 64;
      float4 v = *(const float4*)&A[(size_t)(m0 + ar) * Kdim + kt + kq];
      if constexpr (MODE == 0) {
        float2 st = q ? st1 : st0;
        v.x = (v.x - st.x) * st.y * wa4.x + ba4.x;
        v.y = (v.y - st.x) * st.y * wa4.y + ba4.y;
        v.z = (v.z - st.x) * st.y * wa4.z + ba4.z;
        v.w = (v.w - st.x) * st.y * wa4.w + ba4.w;
      }
      As[kq + 0][ar] = v.x; As[kq + 1][ar] = v.y;
      As[kq + 2][ar] = v.z; As[kq + 3][ar] = v.w;
    }
#pragma unroll
    for (int q = 0; q < 2; q++) {
      int br = brow + q * 8;
      *(float4*)&Bs[br][bcol] =
          *(const float4*)&Bp[(size_t)(kt + br) * Ndim + n0 + bcol];
    }
    __syncthreads();
#pragma unroll
    for (int k = 0; k < 16; k++) {
      float4 a0 = *(const float4*)&As[k][ty * 8];
      float4 a1 = *(const float4*)&As[k][ty * 8 + 4];
      float4 b0 = *(const float4*)&Bs[k][tx * 8];
      float4 b1 = *(const float4*)&Bs[k][tx * 8 + 4];
      float av[8] = {a0.x, a0.y, a0.z, a0.w, a1.x, a1.y, a1.z, a1.w};
      float bv[8] = {b0.x, b0.y, b0.z, b0.w, b1.x, b1.y, b1.z, b1.w};
#pragma unroll
      for (int i = 0; i < 8; i++)
#pragma unroll
        for (int j = 0; j < 8; j++) acc[i][j] += av[i] * bv[j];
    }
    __syncthreads();
  }

  const int col0 = n0 + tx * 8;
  if constexpr (MODE == 0) {
    int h = (col0 & 255) >> 5;
    int d0 = col0 & 31;
    float bb[8];
#pragma unroll
    for (int j = 0; j < 8; j++) bb[j] = biasp[col0 + j];
#pragma unroll
    for (int i = 0; i < 8; i++) {
      int r = m0 + ty * 8 + i;
      int bp = r >> 5, cc = r & 31;
      float* dst = outsel + (((size_t)(bp * 8 + h) * 32 + cc) * 32 + d0);
      *(float4*)dst = make_float4(acc[i][0] + bb[0], acc[i][1] + bb[1],
                                  acc[i][2] + bb[2], acc[i][3] + bb[3]);
      *(float4*)(dst + 4) = make_float4(acc[i][4] + bb[4], acc[i][5] + bb[5],
                                        acc[i][6] + bb[6], acc[i][7] + bb[7]);
    }
  } else if constexpr (MODE == 1) {
    float bb[8];
#pragma unroll
    for (int j = 0; j < 8; j++) bb[j] = bias0[col0 + j];
#pragma unroll
    for (int i = 0; i < 8; i++) {
      int r = m0 + ty * 8 + i;
      float vv[8];
#pragma unroll
      for (int j = 0; j < 8; j++) {
        float v = acc[i][j] + bb[j];
        vv[j] = 0.5f * v * (1.0f + erff(v * 0.70710678118654752f));
      }
      float* dst = out0 + (size_t)r * Ndim + col0;
      *(float4*)dst = make_float4(vv[0], vv[1], vv[2], vv[3]);
      *(float4*)(dst + 4) = make_float4(vv[4], vv[5], vv[6], vv[7]);
    }
  } else {
    float bb[8];
#pragma unroll
    for (int j = 0; j < 8; j++) bb[j] = bias0[col0 + j];
#pragma unroll
    for (int i = 0; i < 8; i++) {
      int r = m0 + ty * 8 + i;
      const float* rp = res + (size_t)r * Ndim + col0;
      float4 r0 = *(const float4*)rp;
      float4 r1 = *(const float4*)(rp + 4);
      float* dst = out0 + (size_t)r * Ndim + col0;
      *(float4*)dst = make_float4(acc[i][0] + bb[0] + r0.x, acc[i][1] + bb[1] + r0.y,
                                  acc[i][2] + bb[2] + r0.z, acc[i][3] + bb[3] + r0.w);
      *(float4*)(dst + 4) = make_float4(acc[i][4] + bb[4] + r1.x, acc[i][5] + bb[5] + r1.y,
                                        acc[i][6] + bb[6] + r1.z, acc[i][7] + bb[7] + r1.w);
    }
  }
}

// ---------------- weight transpose + bf16 convert: W[K][N] -> Wt[N][K] ----------------
__global__ __launch_bounds__(256) void trans_bf16(const float* __restrict__ W,
    bf16_t* __restrict__ Wt, int K, int N) {
  __shared__ float tile[32][33];
  int tx = threadIdx.x & 31, ty = threadIdx.x >> 5;
  int k0 = blockIdx.x * 32, n0 = blockIdx.y * 32;
#pragma unroll
  for (int i = 0; i < 4; i++)
    tile[ty + 8 * i][tx] = W[(size_t)(k0 + ty + 8 * i) * N + n0 + tx];
  __syncthreads();
#pragma unroll
  for (int i = 0; i < 4; i++)
    Wt[(size_t)(n0 + ty + 8 * i) * K + k0 + tx] = (bf16_t)tile[tx][ty + 8 * i];
}

// ---------------- split z -> zr_bf, zi_bf ([512][16256] bf16) ----------------
__global__ __launch_bounds__(256) void zsplit_bf16(const float* __restrict__ z,
    bf16_t* __restrict__ zr, bf16_t* __restrict__ zi) {
  int idx = blockIdx.x * 256 + threadIdx.x;  // 512*4064
  int k4 = idx % 4064;
  int row = idx / 4064;
  int k0 = k4 * 4;
  int b = row >> 5, c = row & 31;
  int p = k0 >> 7, dd = k0 & 127;
  size_t src = ((size_t)((b * 127 + p) * 32 + c)) * 256 + dd;
  float4 vr = *(const float4*)&z[src];
  float4 vi = *(const float4*)&z[src + 128];
  BPack pk;
  pk.e[0] = (bf16_t)vr.x; pk.e[1] = (bf16_t)vr.y;
  pk.e[2] = (bf16_t)vr.z; pk.e[3] = (bf16_t)vr.w;
  pk.e[4] = (bf16_t)vi.x; pk.e[5] = (bf16_t)vi.y;
  pk.e[6] = (bf16_t)vi.z; pk.e[7] = (bf16_t)vi.w;
  *(uint2*)&zr[(size_t)row * 16256 + k0] = make_uint2(pk.u.x, pk.u.y);
  *(uint2*)&zi[(size_t)row * 16256 + k0] = make_uint2(pk.u.z, pk.u.w);
}

// ---------------- bf16 MFMA GEMM 128x128, 16x16x32 ----------------
// MODE 0: QKV (A=z f32, fused LN, permuted f32 store)
// MODE 1: FFN1 (A=ao f32, GELU, bf16 store)
// MODE 2: FFN2 (A=hidden bf16, +bias+res, f32 store)
// MODE 3: PROJ (A=zr/zi bf16, split-K 4x4064, raw partial f32 store)
template <int MODE>
__global__ __launch_bounds__(256) void gemm_bf16_k(
    const float* __restrict__ Af, const bf16_t* __restrict__ Abf,
    const bf16_t* __restrict__ W0, const bf16_t* __restrict__ W1, const bf16_t* __restrict__ W2,
    const float* __restrict__ bias0, const float* __restrict__ bias1, const float* __restrict__ bias2,
    const float2* __restrict__ stats, const float* __restrict__ lnw, const float* __restrict__ lnb,
    const float* __restrict__ res,
    float* __restrict__ out0, float* __restrict__ out1, float* __restrict__ out2,
    bf16_t* __restrict__ outbf) {
  constexpr int KW = (MODE == 2) ? 1024 : ((MODE == 3) ? 16256 : 256);
  constexpr int KEFF = (MODE == 3) ? 4064 : KW;
  __shared__ bf16_t As[128][32];
  __shared__ bf16_t Bs[128][32];
  const int tid = threadIdx.x;
  const int bm = blockIdx.x, bn = blockIdx.y;
  const int m0 = bm * 128;
  const int r2 = tid >> 1, kh = (tid & 1) * 16;

  const bf16_t* Wp = W0;
  const float* biasp = bias0;
  float* qkvout = out0;
  int nW0 = bn * 128;
  int kbase = 0;
  if constexpr (MODE == 0) {
    int sel = bn >> 1;
    Wp = sel == 0 ? W0 : (sel == 1 ? W1 : W2);
    biasp = sel == 0 ? bias0 : (sel == 1 ? bias1 : bias2);
    qkvout = sel == 0 ? out0 : (sel == 1 ? out1 : out2);
    nW0 = (bn & 1) * 128;
  }
  const bf16_t* Ab = Abf;
  if constexpr (MODE == 3) {
    int bz = blockIdx.z;
    kbase = (bz & 3) * 4064;
    if (bz >= 4) { Wp = W1; Ab += 8323072; }
  }

  f4v acc[2][8];
#pragma unroll
  for (int i = 0; i < 2; i++)
#pragma unroll
    for (int j = 0; j < 8; j++) { acc[i][j][0] = 0.f; acc[i][j][1] = 0.f; acc[i][j][2] = 0.f; acc[i][j][3] = 0.f; }

  float2 st;
  if constexpr (MODE == 0) st = stats[m0 + r2];

  const int lane = tid & 63, wvi = tid >> 6;
  const int fm = lane & 15, fq = lane >> 4;

  for (int kt = 0; kt < KEFF; kt += 32) {
    // ---- stage A ----
    if constexpr (MODE == 0 || MODE == 1) {
      const float* ap = Af + (size_t)(m0 + r2) * 256 + kt + kh;
      float vv[16];
      *(float4*)&vv[0]  = *(const float4*)(ap);
      *(float4*)&vv[4]  = *(const float4*)(ap + 4);
      *(float4*)&vv[8]  = *(const float4*)(ap + 8);
      *(float4*)&vv[12] = *(const float4*)(ap + 12);
      if constexpr (MODE == 0) {
        float wvv[16], bvv[16];
        *(float4*)&wvv[0]  = *(const float4*)&lnw[kt + kh];
        *(float4*)&wvv[4]  = *(const float4*)&lnw[kt + kh + 4];
        *(float4*)&wvv[8]  = *(const float4*)&lnw[kt + kh + 8];
        *(float4*)&wvv[12] = *(const float4*)&lnw[kt + kh + 12];
        *(float4*)&bvv[0]  = *(const float4*)&lnb[kt + kh];
        *(float4*)&bvv[4]  = *(const float4*)&lnb[kt + kh + 4];
        *(float4*)&bvv[8]  = *(const float4*)&lnb[kt + kh + 8];
        *(float4*)&bvv[12] = *(const float4*)&lnb[kt + kh + 12];
#pragma unroll
        for (int j = 0; j < 16; j++) vv[j] = (vv[j] - st.x) * st.y * wvv[j] + bvv[j];
      }
      BPack p0, p1;
#pragma unroll
      for (int j = 0; j < 8; j++) { p0.e[j] = (bf16_t)vv[j]; p1.e[j] = (bf16_t)vv[8 + j]; }
      *(uint4*)&As[r2][kh] = p0.u;
      *(uint4*)&As[r2][kh + 8] = p1.u;
    } else {
      const bf16_t* ap = Ab + (size_t)(m0 + r2) * ((MODE == 2) ? 1024 : 16256) + kbase + kt + kh;
      *(uint4*)&As[r2][kh] = *(const uint4*)ap;
      *(uint4*)&As[r2][kh + 8] = *(const uint4*)(ap + 8);
    }
    // ---- stage B ----
    {
      const bf16_t* wp = Wp + (size_t)(nW0 + r2) * KW + kbase + kt + kh;
      *(uint4*)&Bs[r2][kh] = *(const uint4*)wp;
      *(uint4*)&Bs[r2][kh + 8] = *(const uint4*)(wp + 8);
    }
    __syncthreads();
    bf8v a0 = *(const bf8v*)&As[wvi * 32 + fm][fq * 8];
    bf8v a1 = *(const bf8v*)&As[wvi * 32 + 16 + fm][fq * 8];
#pragma unroll
    for (int j = 0; j < 8; j++) {
      bf8v b = *(const bf8v*)&Bs[j * 16 + fm][fq * 8];
      acc[0][j] = __builtin_amdgcn_mfma_f32_16x16x32_bf16(a0, b, acc[0][j], 0, 0, 0);
      acc[1][j] = __builtin_amdgcn_mfma_f32_16x16x32_bf16(a1, b, acc[1][j], 0, 0, 0);
    }
    __syncthreads();
  }

  // ---- epilogue ----
#pragma unroll
  for (int i = 0; i < 2; i++) {
    int rl = m0 + wvi * 32 + i * 16 + fq * 4;
#pragma unroll
    for (int j = 0; j < 8; j++) {
      int cl = j * 16 + fm;
      if constexpr (MODE == 0) {
        int cg = nW0 + cl;
        float bb = biasp[cg];
        int h = cg >> 5, d = cg & 31;
#pragma unroll
        for (int r = 0; r < 4; r++) {
          int rg = rl + r;
          int bpL = rg >> 5, cc = rg & 31;
          qkvout[((size_t)(bpL * 8 + h) * 32 + cc) * 32 + d] = acc[i][j][r] + bb;
        }
      } else if constexpr (MODE == 1) {
        int cg = bn * 128 + cl;
        float bb = bias0[cg];
#pragma unroll
        for (int r = 0; r < 4; r++) {
          int rg = rl + r;
          float v = acc[i][j][r] + bb;
          v = 0.5f * v * (1.0f + erff(v * 0.70710678118654752f));
          outbf[(size_t)rg * 1024 + cg] = (bf16_t)v;
        }
      } else if constexpr (MODE == 2) {
        int cg = bn * 128 + cl;
        float bb = bias0[cg];
#pragma unroll
        for (int r = 0; r < 4; r++) {
          int rg = rl + r;
          out0[(size_t)rg * 256 + cg] = acc[i][j][r] + bb + res[(size_t)rg * 256 + cg];
        }
      } else {
        int cg = bn * 128 + cl;
        float* dst = out0 + (size_t)blockIdx.z * 524288 + (size_t)cg;
#pragma unroll
        for (int r = 0; r < 4; r++) {
          int rg = rl + r;
          dst[(size_t)rg * 1024] = acc[i][j][r];
        }
      }
    }
  }
}

// ---------------- lightweight masked attention (per bp in chunk) ----------------
__global__ __launch_bounds__(256) void attn2_kernel(const float* __restrict__ Qb,
    const float* __restrict__ Kb, const float* __restrict__ Vb,
    const float* __restrict__ mask, const float* __restrict__ z, float* __restrict__ ao,
    float* __restrict__ out4, float* __restrict__ out5) {
  __shared__ float Qs[32][33], Ks[32][33], Vs[32][33], Ps[32][33];
  __shared__ float mk[32][32];
  __shared__ float red[32][8];
  int tid = threadIdx.x, bp = blockIdx.x;
  {
    float4 v = ((const float4*)(mask + (size_t)bp * 1024))[tid];
    int c = tid >> 3, e0 = (tid & 7) * 4;
    mk[c][e0] = v.x; mk[c][e0 + 1] = v.y; mk[c][e0 + 2] = v.z; mk[c][e0 + 3] = v.w;
  }
  const int c = tid >> 3, g = tid & 7, e0 = g * 4;
  float am[4] = {0, 0, 0, 0}, mm[4] = {0, 0, 0, 0};
  const float scale = 0.17677669529663687f;
  for (int h = 0; h < 8; h++) {
    __syncthreads();
    {
      size_t base = ((size_t)(bp * 8 + h) << 10) + tid * 4;
      float4 q = *(const float4*)&Qb[base];
      float4 k = *(const float4*)&Kb[base];
      float4 v = *(const float4*)&Vb[base];
      int cc = tid >> 3, d0 = (tid & 7) * 4;
      Qs[cc][d0] = q.x; Qs[cc][d0 + 1] = q.y; Qs[cc][d0 + 2] = q.z; Qs[cc][d0 + 3] = q.w;
      Ks[cc][d0] = k.x; Ks[cc][d0 + 1] = k.y; Ks[cc][d0 + 2] = k.z; Ks[cc][d0 + 3] = k.w;
      Vs[cc][d0] = v.x; Vs[cc][d0 + 1] = v.y; Vs[cc][d0 + 2] = v.z; Vs[cc][d0 + 3] = v.w;
    }
    __syncthreads();
    float sv[4];
#pragma unroll
    for (int j = 0; j < 4; j++) {
      int e = e0 + j;
      float s = 0.f;
#pragma unroll
      for (int d = 0; d < 32; d += 4)
        s += Qs[c][d] * Ks[e][d] + Qs[c][d + 1] * Ks[e][d + 1] +
             Qs[c][d + 2] * Ks[e][d + 2] + Qs[c][d + 3] * Ks[e][d + 3];
      float a = s * scale;
      am[j] += a;
      float smv = (mk[c][e] > 0.5f) ? a : -1e9f;
      mm[j] += smv;
      sv[j] = smv;
    }
    red[c][g] = fmaxf(fmaxf(sv[0], sv[1]), fmaxf(sv[2], sv[3]));
    __syncthreads();
    float mx = red[c][0];
#pragma unroll
    for (int j = 1; j < 8; j++) mx = fmaxf(mx, red[c][j]);
    __syncthreads();
    float ev[4], ls = 0.f;
#pragma unroll
    for (int j = 0; j < 4; j++) { ev[j] = expf(sv[j] - mx); ls += ev[j]; }
    red[c][g] = ls;
    __syncthreads();
    float sum = 0.f;
#pragma unroll
    for (int j = 0; j < 8; j++) sum += red[c][j];
    float inv = 1.0f / sum;
#pragma unroll
    for (int j = 0; j < 4; j++) Ps[c][e0 + j] = ev[j] * inv;
    __syncthreads();
    {
      int d0 = (tid & 7) * 4;
      float o0 = 0, o1 = 0, o2 = 0, o3 = 0;
#pragma unroll
      for (int e = 0; e < 32; e++) {
        float p = Ps[c][e];
        o0 += p * Vs[e][d0]; o1 += p * Vs[e][d0 + 1];
        o2 += p * Vs[e][d0 + 2]; o3 += p * Vs[e][d0 + 3];
      }
      size_t gi = ((size_t)(bp * 32 + c)) * 256 + h * 32 + d0;
      float4 zr = *(const float4*)&z[gi];
      *(float4*)&ao[gi] = make_float4(o0 + zr.x, o1 + zr.y, o2 + zr.z, o3 + zr.w);
    }
  }
  size_t ob = (size_t)bp * 1024 + c * 32 + e0;
#pragma unroll
  for (int j = 0; j < 4; j++) {
    out4[ob + j] = am[j] * 0.125f;
    out5[ob + j] = mm[j] * 0.125f;
  }
}

// ---------------- split-K reduce + bias for final projection ----------------
__global__ __launch_bounds__(256) void reduce_kernel(const float* __restrict__ partial,
    const float* __restrict__ pr_b, const float* __restrict__ pi_b,
    float* __restrict__ xrr, float* __restrict__ xir) {
  int idx = blockIdx.x * 256 + threadIdx.x;  // 524288
  int l = idx & 1023;
  float s = 0.f;
  for (int k = 0; k < 4; k++) s += partial[(size_t)k * 524288 + idx];
  xrr[idx] = s + pr_b[l];
  float t = 0.f;
  for (int k = 4; k < 8; k++) t += partial[(size_t)k * 524288 + idx];
  xir[idx] = t + pi_b[l];
}

// ---------------- inverse FFT + transposed outputs ----------------
__global__ __launch_bounds__(256) void ifft_kernel(const float* __restrict__ xrr,
    const float* __restrict__ xir, float* __restrict__ out0,
    float* __restrict__ out1, float* __restrict__ out2) {
  __shared__ float re[1024], im[1024];
  __shared__ float tw[512][2];
  int tid = threadIdx.x, row = blockIdx.x;
  int b = row >> 5, c = row & 31;
  for (int k = tid; k < 512; k += 256) {
    double a = 2.0 * PI_ * (double)k / 1024.0;
    tw[k][0] = (float)cos(a); tw[k][1] = (float)sin(a);
  }
  for (int l = tid; l < 1024; l += 256) {
    float vr = xrr[row * 1024 + l], vi = xir[row * 1024 + l];
    re[l] = vr; im[l] = vi;
    out1[(b * 1024 + l) * 32 + c] = vr;
    out2[(b * 1024 + l) * 32 + c] = vi;
  }
  __syncthreads();
  for (int i = tid; i < 1024; i += 256) {
    int j = __brev(i) >> 22;
    if (j > i) { float t = re[i]; re[i] = re[j]; re[j] = t; t = im[i]; im[i] = im[j]; im[j] = t; }
  }
  __syncthreads();
  for (int st = 0; st < 10; st++) {
    int half = 1 << st, tstep = 512 >> st;
    for (int bf = tid; bf < 512; bf += 256) {
      int grp = bf >> st, pos = bf & (half - 1);
      int i0 = (grp << (st + 1)) + pos, i1 = i0 + half;
      float wr = tw[pos * tstep][0], wi = tw[pos * tstep][1];
      float ar = re[i1], ai = im[i1];
      float tr = wr * ar - wi * ai, ti = wr * ai + wi * ar;
      re[i1] = re[i0] - tr; im[i1] = im[i0] - ti;
      re[i0] += tr; im[i0] += ti;
    }
    __syncthreads();
  }
  const float invN = 1.0f / 1024.0f;
  for (int l = tid; l < 1024; l += 256)
    out0[(b * 1024 + l) * 32 + c] = re[l] * invN;
}

// ---------------- host ----------------
extern "C" void kernel_launch(void* const* d_in, const int* in_sizes, int n_in,
                              void* d_out, int out_size, void* d_ws, size_t ws_size,
                              hipStream_t stream) {
  const float* x      = (const float*)d_in[0];
  const float* in_w   = (const float*)d_in[1];
  const float* in_b   = (const float*)d_in[2];
  const float* proj_w = (const float*)d_in[3];
  const float* proj_b = (const float*)d_in[4];
  const float* mg_w1  = (const float*)d_in[5];
  const float* mg_b1  = (const float*)d_in[6];
  const float* mg_w2  = (const float*)d_in[7];
  const float* mg_b2  = (const float*)d_in[8];
  const float* ln_w   = (const float*)d_in[9];
  const float* ln_b   = (const float*)d_in[10];
  const float* wq     = (const float*)d_in[11];
  const float* bq     = (const float*)d_in[12];
  const float* wk     = (const float*)d_in[13];
  const float* bk     = (const float*)d_in[14];
  const float* wv     = (const float*)d_in[15];
  const float* bv     = (const float*)d_in[16];
  const float* ffn_w1 = (const float*)d_in[17];
  const float* ffn_b1 = (const float*)d_in[18];
  const float* ffn_w2 = (const float*)d_in[19];
  const float* ffn_b2 = (const float*)d_in[20];
  const float* pr_b   = (const float*)d_in[22];
  const float* pi_b   = (const float*)d_in[24];
  const float* pr_w   = (const float*)d_in[21];
  const float* pi_w   = (const float*)d_in[23];
  float* out = (float*)d_out;

  // Arena (peak ~203.5 MB):
  //   z 66.58M | Qb/Kb/Vb/ao 4x16.65M (post-layers: WtR+WtI 66.58M)
  //   H 66.58M: xr64/xi64 | hidden(f32 L0)/hidden_bf(L1) | zr_bf+zi_bf+partial+xrr+xir
  //   E: maskb, stats, w2m, b2m, WtQ/K/V, Wt1, Wt2
  char* wsp = (char*)d_ws;
  float*  z      = (float*)(wsp);
  float*  Qb     = (float*)(wsp + 66584576ull);
  float*  Kb     = (float*)(wsp + 83230720ull);
  float*  Vb     = (float*)(wsp + 99876864ull);
  float*  ao     = (float*)(wsp + 116523008ull);
  char*   Hreg   = wsp + 133169152ull;
  float*  hidden = (float*)Hreg;
  bf16_t* hidden_bf = (bf16_t*)Hreg;
  double* xr64   = (double*)Hreg;
  double* xi64   = (double*)(Hreg + 4194304ull);
  bf16_t* zr_bf  = (bf16_t*)Hreg;
  bf16_t* zi_bf  = (bf16_t*)(Hreg + 16646144ull);
  float*  partial= (float*)(Hreg + 33292288ull);
  float*  xrr    = (float*)(Hreg + 50069504ull);
  float*  xir    = (float*)(Hreg + 52166656ull);
  bf16_t* WtR    = (bf16_t*)(wsp + 66584576ull);             // aliases Q-region (post-layers)
  bf16_t* WtI    = (bf16_t*)(wsp + 66584576ull + 33292288ull);
  char*   Ereg   = wsp + 199753728ull;
  float*  maskb  = (float*)Ereg;
  float2* stats  = (float2*)(Ereg + 2080768ull);
  double* w2m    = (double*)(Ereg + 2210816ull);
  double* b2m    = (double*)(Ereg + 2276352ull);
  bf16_t* WtQ    = (bf16_t*)(Ereg + 2276608ull);
  bf16_t* WtK    = (bf16_t*)(Ereg + 2407680ull);
  bf16_t* WtV    = (bf16_t*)(Ereg + 2538752ull);
  bf16_t* Wt1    = (bf16_t*)(Ereg + 2669824ull);
  bf16_t* Wt2    = (bf16_t*)(Ereg + 3194112ull);
  size_t need = 199753728ull + 3718400ull;
  if (ws_size < need) return;

  uint32_t fk0[2], fk1[2];
  for (int l = 0; l < 2; l++) {
    uint32_t a, b;
    tf2x32(0u, 42u, 0u, (uint32_t)l, a, b);
    fk0[l] = a; fk1[l] = b;
  }

  ln_fft_kernel<<<512, 256, 0, stream>>>(x, in_w, in_b, xr64, xi64);
  patch_proj_kernel<<<2032, 256, 0, stream>>>(xr64, xi64, proj_w, proj_b, z);

  // layer-1 weight prep (bf16 transposes)
  trans_bf16<<<dim3(8, 8), 256, 0, stream>>>(wq + 65536, WtQ, 256, 256);
  trans_bf16<<<dim3(8, 8), 256, 0, stream>>>(wk + 65536, WtK, 256, 256);
  trans_bf16<<<dim3(8, 8), 256, 0, stream>>>(wv + 65536, WtV, 256, 256);
  trans_bf16<<<dim3(8, 32), 256, 0, stream>>>(ffn_w1 + 262144, Wt1, 256, 1024);
  trans_bf16<<<dim3(32, 8), 256, 0, stream>>>(ffn_w2 + 262144, Wt2, 1024, 256);

  float* O3 = out + 1572864;
  float* O4 = out + 5734400;
  float* O5 = out + 9895936;
  for (int l = 0; l < 2; l++) {
    w2m_kernel<<<33, 256, 0, stream>>>(mg_w2 + l * 262144, mg_b2 + l * 1024, w2m, b2m);
    for (int ch = 0; ch < 4; ch++) {
      int bp0 = ch * 508;
      float* zc = z + (size_t)bp0 * 8192;
      mask_kernel<<<508, 256, 0, stream>>>(zc, mg_w1 + l * 65536, mg_b1 + l * 256,
                                           w2m, b2m, fk0[l], fk1[l], bp0,
                                           maskb, O3 + l * 2080768);
      lnstats_kernel<<<4064, 256, 0, stream>>>(zc, stats);
      if (l == 0) {
        gemm128<0><<<dim3(127, 6), 256, 0, stream>>>(
            zc, wq, wk, wv, bq, bk, bv,
            stats, ln_w, ln_b, nullptr, Qb, Kb, Vb, 256, 256);
      } else {
        gemm_bf16_k<0><<<dim3(127, 6), 256, 0, stream>>>(
            zc, nullptr, WtQ, WtK, WtV, bq + 256, bk + 256, bv + 256,
            stats, ln_w + 256, ln_b + 256, nullptr, Qb, Kb, Vb, nullptr);
      }
      attn2_kernel<<<508, 256, 0, stream>>>(Qb, Kb, Vb, maskb, zc, ao,
                                            O4 + l * 2080768 + (size_t)bp0 * 1024,
                                            O5 + l * 2080768 + (size_t)bp0 * 1024);
      if (l == 0) {
        gemm128<1><<<dim3(127, 8), 256, 0, stream>>>(
            ao, ffn_w1, nullptr, nullptr, ffn_b1, nullptr, nullptr,
            nullptr, nullptr, nullptr, nullptr, hidden, nullptr, nullptr, 256, 1024);
        gemm128<2><<<dim3(127, 2), 256, 0, stream>>>(
            hidden, ffn_w2, nullptr, nullptr, ffn_b2, nullptr, nullptr,
            nullptr, nullptr, nullptr, ao, zc, nullptr, nullptr, 1024, 256);
      } else {
        gemm_bf16_k<1><<<dim3(127, 8), 256, 0, stream>>>(
            ao, nullptr, Wt1, nullptr, nullptr, ffn_b1 + 1024, nullptr, nullptr,
            nullptr, nullptr, nullptr, nullptr, nullptr, nullptr, nullptr, hidden_bf);
        gemm_bf16_k<2><<<dim3(127, 2), 256, 0, stream>>>(
            nullptr, hidden_bf, Wt2, nullptr, nullptr, ffn_b2 + 256, nullptr, nullptr,
            nullptr, nullptr, nullptr, ao, zc, nullptr, nullptr, nullptr);
      }
    }
  }
  // final projection: transpose big weights into freed Q-region, split z, MFMA split-K
  trans_bf16<<<dim3(508, 32), 256, 0, stream>>>(pr_w, WtR, 16256, 1024);
  trans_bf16<<<dim3(508, 32), 256, 0, stream>>>(pi_w, WtI, 16256, 1024);
  zsplit_bf16<<<8128, 256, 0, stream>>>(z, zr_bf, zi_bf);
  gemm_bf16_k<3><<<dim3(4, 8, 8), 256, 0, stream>>>(
      nullptr, zr_bf, WtR, WtI, nullptr, nullptr, nullptr, nullptr,
      nullptr, nullptr, nullptr, nullptr, partial, nullptr, nullptr, nullptr);
  reduce_kernel<<<2048, 256, 0, stream>>>(partial, pr_b, pi_b, xrr, xir);
  ifft_kernel<<<512, 256, 0, stream>>>(xrr, xir, out, out + 524288, out + 1048576);
}